// Round 4
// baseline (272.865 us; speedup 1.0000x reference)
//
#include <hip/hip_runtime.h>

// PQHead forward: out[b, m*6+d] = codebooks[m, argmax_k dot(x[b,m,:], cb[m,k,:]), d]
// (straight-through estimator: forward value of quant is exactly `discrete`)
//
// R4: ILP fix. R3 evidence: VGPR=60, VALUBusy 40% -> compiler serialized the
// row loop to save registers. Now: __launch_bounds__(256,4) = 128-VGPR budget,
// double-buffered LDS (ONE barrier per stage), LDS reads grouped 4 rows ahead
// of their compute so 4 independent argmax chains are in flight per wave.

#define BATCH 32768
#define DIM   768
#define K_CB  32
#define D_SUB 6
#define KPT   8                // codes per thread (k split 4 ways)
#define BROWS 32               // rows per block
#define RSTG  8                // rows per LDS stage
#define NSTG  (BROWS/RSTG)     // 4 stages
#define HALFF 384              // floats per half row (64 m * 6)
#define STGF  (RSTG*HALFF)     // 3072 floats = 12 KiB per buffer
#define RG    4                // rows per compute group (ILP width)

__global__ __launch_bounds__(256, 4)
void pq_head_kernel(const float* __restrict__ x,
                    const float* __restrict__ cb,
                    float* __restrict__ out) {
    __shared__ float xs[2][STGF];   // 24 KiB double buffer

    const int t     = threadIdx.x;
    const int kq    = t & 3;        // k-quarter
    const int mloc  = t >> 2;       // 0..63
    const int mhalf = blockIdx.y;   // 0/1
    const int m     = mhalf * 64 + mloc;
    const int b0    = blockIdx.x * BROWS;

    // This lane's 8 codebook rows (48 floats), 192-B aligned base -> 12 float4.
    float c[KPT * D_SUB];
    {
        const float4* cb4 = reinterpret_cast<const float4*>(
            cb + ((size_t)m * K_CB + (size_t)kq * KPT) * D_SUB);
        #pragma unroll
        for (int i = 0; i < 12; ++i) {
            float4 v = cb4[i];
            c[4*i+0]=v.x; c[4*i+1]=v.y; c[4*i+2]=v.z; c[4*i+3]=v.w;
        }
    }

    const float* xh = x   + (size_t)mhalf * HALFF;  // half-row base
    float*       oh = out + (size_t)mhalf * HALFF;

    // Per-thread (row, col) for the coalesced stage load: stage-invariant.
    int pr[3], pc[3];
    #pragma unroll
    for (int i = 0; i < 3; ++i) {
        int f = (i * 256 + t) * 4;          // float index within stage (<3072)
        pr[i] = f / HALFF;                  // 0..7
        pc[i] = f - pr[i] * HALFF;
    }

    // Prefetch stage 0 (3 x dwordx4 per thread, fully coalesced).
    float4 pf[3];
    #pragma unroll
    for (int i = 0; i < 3; ++i)
        pf[i] = *reinterpret_cast<const float4*>(xh + (size_t)(b0 + pr[i]) * DIM + pc[i]);

    for (int s = 0; s < NSTG; ++s) {
        float* buf = xs[s & 1];
        #pragma unroll
        for (int i = 0; i < 3; ++i)
            *reinterpret_cast<float4*>(&buf[(i * 256 + t) * 4]) = pf[i];
        __syncthreads();   // single barrier per stage: writers of buf done;
                           // readers of the OTHER buffer finished before the
                           // previous barrier, so next stage's writes are safe.

        if (s + 1 < NSTG) {                 // prefetch next stage now; consumer
            int rb = b0 + (s + 1) * RSTG;   // (ds_write) is a full stage away
            #pragma unroll
            for (int i = 0; i < 3; ++i)
                pf[i] = *reinterpret_cast<const float4*>(
                    xh + (size_t)(rb + pr[i]) * DIM + pc[i]);
        }

        #pragma unroll
        for (int g = 0; g < RSTG; g += RG) {
            // ---- hoisted LDS reads: RG independent rows ----
            float xv[RG][D_SUB];
            #pragma unroll
            for (int rr = 0; rr < RG; ++rr) {
                const float* xr = &buf[(g + rr) * HALFF + mloc * D_SUB];
                float2 x01 = *reinterpret_cast<const float2*>(xr);
                float2 x23 = *reinterpret_cast<const float2*>(xr + 2);
                float2 x45 = *reinterpret_cast<const float2*>(xr + 4);
                xv[rr][0]=x01.x; xv[rr][1]=x01.y; xv[rr][2]=x23.x;
                xv[rr][3]=x23.y; xv[rr][4]=x45.x; xv[rr][5]=x45.y;
            }

            // ---- RG independent winner computations ----
            #pragma unroll
            for (int rr = 0; rr < RG; ++rr) {
                int b = b0 + s * RSTG + g + rr;

                float best1 = -3.402823466e+38f;
                float best2 = -3.402823466e+38f;
                int   kg    = kq * KPT;
                #pragma unroll
                for (int j = 0; j < KPT; ++j) {
                    float d = c[j*6+0] * xv[rr][0];
                    #pragma unroll
                    for (int e = 1; e < 6; ++e) d = fmaf(c[j*6+e], xv[rr][e], d);
                    bool gt = d > best1;              // strict > => first index wins
                    best2 = gt ? best1 : fmaxf(best2, d);
                    kg    = gt ? (kq * KPT + j) : kg;
                    best1 = gt ? d : best1;
                }

                // butterfly merge across the quad (lanes share (b,m), split k)
                #pragma unroll
                for (int sft = 1; sft <= 2; sft <<= 1) {
                    float o1 = __shfl_xor(best1, sft);
                    float o2 = __shfl_xor(best2, sft);
                    int   ok = __shfl_xor(kg,    sft);
                    bool take = (o1 > best1) || (o1 == best1 && ok < kg);
                    best2 = fmaxf(fminf(best1, o1), fmaxf(best2, o2));
                    kg    = take ? ok : kg;
                    best1 = fmaxf(best1, o1);
                }

                // Near-tie (quad-uniform, ~0.05%): exact fp64 argmax.
                if (best1 - best2 < 1e-5f) {
                    const float* crow = cb + (size_t)m * K_CB * D_SUB;
                    double db = -1e300; int dkg = 0;
                    for (int k2 = 0; k2 < K_CB; ++k2) {
                        double sa = 0.0;
                        for (int e = 0; e < 6; ++e)
                            sa = fma((double)crow[k2*6+e], (double)xv[rr][e], sa);
                        if (sa > db) { db = sa; dkg = k2; }
                    }
                    kg = dkg;
                }

                // Gather winner row (cb L1/L2-hot) and store float2.
                if (kq < 3) {
                    float2 gv = *(reinterpret_cast<const float2*>(
                        cb + ((size_t)m * K_CB + (size_t)kg) * D_SUB) + kq);
                    *(reinterpret_cast<float2*>(oh + (size_t)b * DIM) + (mloc * 3 + kq)) = gv;
                }
            }
        }
    }
}

extern "C" void kernel_launch(void* const* d_in, const int* in_sizes, int n_in,
                              void* d_out, int out_size, void* d_ws, size_t ws_size,
                              hipStream_t stream) {
    const float* x  = (const float*)d_in[0];   // (32768, 768) fp32
    const float* cb = (const float*)d_in[1];   // (128, 32, 6) fp32
    float* out = (float*)d_out;                // (32768, 768) fp32

    dim3 grid(BATCH / BROWS, 2);   // 1024 x 2 = 2048 blocks
    dim3 block(256);               // 64 m x 4 k-quarters
    hipLaunchKernelGGL(pq_head_kernel, grid, block, 0, stream, x, cb, out);
}

// Round 5
// 258.056 us; speedup vs baseline: 1.0574x; 1.0574x over previous
//
#include <hip/hip_runtime.h>

// PQHead forward: out[b, m*6+d] = codebooks[m, argmax_k dot(x[b,m,:], cb[m,k,:]), d]
// (straight-through estimator: forward value of quant is exactly `discrete`)
//
// R5: latency removal. R3/R4 evidence: compiler serializes vector state; the
// per-task tail (2x ds_bpermute shuffle + global winner-gather, ~300 cyc) was
// the exposed latency. Now: DPP quad_perm merges (1-cyc VALU), winner values
// extracted from the owning lane's registers via a cndmask tree, exec-masked
// direct store. No cross-lane memory ops, no gather. LDS staging as in R3.

#define BATCH 32768
#define DIM   768
#define K_CB  32
#define D_SUB 6
#define KPT   8                // codes per thread (k split 4 ways across quad)
#define BROWS 32               // rows per block
#define RSTG  8                // rows per LDS stage
#define HALFF 384              // floats per half row (64 m * 6)
#define STGF  (RSTG*HALFF)     // 3072 floats = 12 KiB

#define DPP_XOR1 0xB1          // quad_perm [1,0,3,2]
#define DPP_XOR2 0x4E          // quad_perm [2,3,0,1]

template<int CTRL>
__device__ __forceinline__ float dppf(float v) {
    return __int_as_float(__builtin_amdgcn_update_dpp(
        0, __float_as_int(v), CTRL, 0xF, 0xF, true));
}
template<int CTRL>
__device__ __forceinline__ int dppi(int v) {
    return __builtin_amdgcn_update_dpp(0, v, CTRL, 0xF, 0xF, true);
}

__global__ __launch_bounds__(256)
void pq_head_kernel(const float* __restrict__ x,
                    const float* __restrict__ cb,
                    float* __restrict__ out) {
    __shared__ float xs[STGF];

    const int t     = threadIdx.x;
    const int kq    = t & 3;        // k-quarter (lane within quad)
    const int mloc  = t >> 2;       // 0..63
    const int mhalf = blockIdx.y;   // 0/1
    const int m     = mhalf * 64 + mloc;
    const int b0    = blockIdx.x * BROWS;

    // This lane's 8 codebook rows (48 floats), 192-B aligned base -> 12 float4.
    float c[KPT * D_SUB];
    {
        const float4* cb4 = reinterpret_cast<const float4*>(
            cb + ((size_t)m * K_CB + (size_t)kq * KPT) * D_SUB);
        #pragma unroll
        for (int i = 0; i < 12; ++i) {
            float4 v = cb4[i];
            c[4*i+0]=v.x; c[4*i+1]=v.y; c[4*i+2]=v.z; c[4*i+3]=v.w;
        }
    }

    const float* xh = x   + (size_t)mhalf * HALFF;  // half-row base
    float*       oh = out + (size_t)mhalf * HALFF;

    // Prefetch stage 0: 3 x float4 per thread, fully coalesced.
    float4 pf[3];
    #pragma unroll
    for (int i = 0; i < 3; ++i) {
        int f   = (i * 256 + t) * 4;      // float index within stage (< 3072)
        int r   = f / HALFF;
        int col = f - r * HALFF;
        pf[i] = *reinterpret_cast<const float4*>(xh + (size_t)(b0 + r) * DIM + col);
    }

    const int NSTG = BROWS / RSTG;
    for (int s = 0; s < NSTG; ++s) {
        __syncthreads();
        #pragma unroll
        for (int i = 0; i < 3; ++i)
            *reinterpret_cast<float4*>(&xs[(i * 256 + t) * 4]) = pf[i];
        __syncthreads();

        if (s + 1 < NSTG) {                 // prefetch next stage now; consumer
            int rb = b0 + (s + 1) * RSTG;   // (ds_write) is across a barrier
            #pragma unroll
            for (int i = 0; i < 3; ++i) {
                int f   = (i * 256 + t) * 4;
                int r   = f / HALFF;
                int col = f - r * HALFF;
                pf[i] = *reinterpret_cast<const float4*>(xh + (size_t)(rb + r) * DIM + col);
            }
        }

        #pragma unroll
        for (int r = 0; r < RSTG; ++r) {
            const int b = b0 + s * RSTG + r;
            const float* xr = &xs[r * HALFF + mloc * D_SUB];   // quad-broadcast
            float2 x01 = *reinterpret_cast<const float2*>(xr);
            float2 x23 = *reinterpret_cast<const float2*>(xr + 2);
            float2 x45 = *reinterpret_cast<const float2*>(xr + 4);
            float xv[6] = {x01.x, x01.y, x23.x, x23.y, x45.x, x45.y};

            // fp32 top-2 + argmax over my 8 codes (strict > => first index wins)
            float best1 = -3.402823466e+38f;
            float best2 = -3.402823466e+38f;
            int   kg    = kq * KPT;
            #pragma unroll
            for (int j = 0; j < KPT; ++j) {
                float d = c[j*6+0] * xv[0];
                #pragma unroll
                for (int e = 1; e < 6; ++e) d = fmaf(c[j*6+e], xv[e], d);
                bool gt = d > best1;
                best2 = gt ? best1 : fmaxf(best2, d);
                kg    = gt ? (kq * KPT + j) : kg;
                best1 = gt ? d : best1;
            }

            // Quad butterfly via DPP (pure VALU, no LDS pipe).
            {
                float o1 = dppf<DPP_XOR1>(best1);
                float o2 = dppf<DPP_XOR1>(best2);
                int   ok = dppi<DPP_XOR1>(kg);
                bool take = (o1 > best1) || (o1 == best1 && ok < kg);
                best2 = fmaxf(fminf(best1, o1), fmaxf(best2, o2));
                kg    = take ? ok : kg;
                best1 = fmaxf(best1, o1);
            }
            {
                float o1 = dppf<DPP_XOR2>(best1);
                float o2 = dppf<DPP_XOR2>(best2);
                int   ok = dppi<DPP_XOR2>(kg);
                bool take = (o1 > best1) || (o1 == best1 && ok < kg);
                best2 = fmaxf(fminf(best1, o1), fmaxf(best2, o2));
                kg    = take ? ok : kg;
                best1 = fmaxf(best1, o1);
            }

            // Near-tie (quad-uniform, rare): exact fp64 argmax over all 32 codes.
            if (best1 - best2 < 1e-5f) {
                const float* crow = cb + (size_t)m * K_CB * D_SUB;
                double db = -1e300; int dkg = 0;
                for (int k2 = 0; k2 < K_CB; ++k2) {
                    double sa = 0.0;
                    for (int e = 0; e < 6; ++e)
                        sa = fma((double)crow[k2*6+e], (double)xv[e], sa);
                    if (sa > db) { db = sa; dkg = k2; }
                }
                kg = dkg;
            }

            // Winner extraction from the OWNING lane's registers: cndmask tree
            // over my 8 codes, selected by j = kg & 7. Deterministic, no memory.
            const int j  = kg & 7;
            const bool s0 = (j & 1), s1b = (j & 2), s2b = (j & 4);
            float t1[4][D_SUB], t2[2][D_SUB], w[D_SUB];
            #pragma unroll
            for (int p = 0; p < 4; ++p)
                #pragma unroll
                for (int e = 0; e < 6; ++e)
                    t1[p][e] = s0 ? c[(2*p+1)*6+e] : c[(2*p)*6+e];
            #pragma unroll
            for (int p = 0; p < 2; ++p)
                #pragma unroll
                for (int e = 0; e < 6; ++e)
                    t2[p][e] = s1b ? t1[2*p+1][e] : t1[2*p][e];
            #pragma unroll
            for (int e = 0; e < 6; ++e)
                w[e] = s2b ? t2[1][e] : t2[0][e];

            // Only the lane owning the winning k-range stores (1 of 4 per quad).
            if ((kg >> 3) == kq) {
                float* dst = oh + (size_t)b * DIM + mloc * D_SUB;  // 8-B aligned
                float2* d2 = reinterpret_cast<float2*>(dst);
                d2[0] = make_float2(w[0], w[1]);
                d2[1] = make_float2(w[2], w[3]);
                d2[2] = make_float2(w[4], w[5]);
            }
        }
    }
}

extern "C" void kernel_launch(void* const* d_in, const int* in_sizes, int n_in,
                              void* d_out, int out_size, void* d_ws, size_t ws_size,
                              hipStream_t stream) {
    const float* x  = (const float*)d_in[0];   // (32768, 768) fp32
    const float* cb = (const float*)d_in[1];   // (128, 32, 6) fp32
    float* out = (float*)d_out;                // (32768, 768) fp32

    dim3 grid(BATCH / BROWS, 2);   // 1024 x 2 = 2048 blocks
    dim3 block(256);               // 64 m x 4 k-quarters
    hipLaunchKernelGGL(pq_head_kernel, grid, block, 0, stream, x, cb, out);
}

// Round 6
// 223.356 us; speedup vs baseline: 1.2217x; 1.1554x over previous
//
#include <hip/hip_runtime.h>
#include <float.h>

// PQHead forward: out[b, m*6+d] = codebooks[m, argmax_k dot(x[b,m,:], cb[m,k,:]), d]
// (straight-through estimator: forward value of quant is exactly `discrete`)
//
// R6: instruction diet + batched tail.
//  - R3 vs R5 evidence: cndmask winner-select tree cost more VALU than the
//    gather latency it removed. Revert to gather, but batch 8 gathers per
//    stage behind a sched_barrier so their latency overlaps.
//  - Dots via v_pk_fma_f32 (code-pair packed v2f), 48 -> 24 instr.
//  - DPP quad merges (R5, proven). LDS x staging + cross-barrier prefetch
//    (R3, proven), now double-buffered with ONE barrier per stage.

typedef float v2f __attribute__((ext_vector_type(2)));

#define BATCH 32768
#define DIM   768
#define K_CB  32
#define D_SUB 6
#define BROWS 16               // rows per block
#define RSTG  8                // rows per LDS stage
#define NSTG  (BROWS/RSTG)     // 2 stages
#define HALFF 384              // floats per half row (64 m * 6)
#define STGF  (RSTG*HALFF)     // 3072 floats = 12 KiB per buffer

#define DPP_XOR1 0xB1          // quad_perm [1,0,3,2]
#define DPP_XOR2 0x4E          // quad_perm [2,3,0,1]

template<int CTRL>
__device__ __forceinline__ float dppf(float v) {
    return __int_as_float(__builtin_amdgcn_update_dpp(
        0, __float_as_int(v), CTRL, 0xF, 0xF, true));
}
template<int CTRL>
__device__ __forceinline__ int dppi(int v) {
    return __builtin_amdgcn_update_dpp(0, v, CTRL, 0xF, 0xF, true);
}

__global__ __launch_bounds__(256, 4)
void pq_head_kernel(const float* __restrict__ x,
                    const float* __restrict__ cb,
                    float* __restrict__ out) {
    __shared__ float xs[2][STGF];   // 24 KiB double buffer

    const int t     = threadIdx.x;
    const int kq    = t & 3;        // k-quarter (lane within quad)
    const int mloc  = t >> 2;       // 0..63
    const int mhalf = blockIdx.y;   // 0/1
    const int m     = mhalf * 64 + mloc;
    const int b0    = blockIdx.x * BROWS;

    // Load this lane's 8 codebook rows (48 floats, 192-B aligned) and pack
    // code-pairs into v2f: cpk[p][e] = (cb[2p][e], cb[2p+1][e]).
    v2f cpk[4][D_SUB];
    {
        float cc[48];
        const float4* cb4 = reinterpret_cast<const float4*>(
            cb + ((size_t)m * K_CB + (size_t)kq * 8) * D_SUB);
        #pragma unroll
        for (int i = 0; i < 12; ++i) {
            float4 v = cb4[i];
            cc[4*i+0]=v.x; cc[4*i+1]=v.y; cc[4*i+2]=v.z; cc[4*i+3]=v.w;
        }
        #pragma unroll
        for (int p = 0; p < 4; ++p)
            #pragma unroll
            for (int e = 0; e < D_SUB; ++e)
                cpk[p][e] = (v2f){cc[(2*p)*D_SUB + e], cc[(2*p+1)*D_SUB + e]};
    }

    const float* xh = x   + (size_t)mhalf * HALFF;  // half-row base
    float*       oh = out + (size_t)mhalf * HALFF;

    // Stage-invariant (row, col) for the coalesced stage load.
    int pr[3], pc[3];
    #pragma unroll
    for (int i = 0; i < 3; ++i) {
        int f = (i * 256 + t) * 4;          // float index within stage (<3072)
        pr[i] = f / HALFF;
        pc[i] = f - pr[i] * HALFF;
    }

    // Prefetch stage 0 (3 x dwordx4 per thread, fully coalesced).
    float4 pf[3];
    #pragma unroll
    for (int i = 0; i < 3; ++i)
        pf[i] = *reinterpret_cast<const float4*>(xh + (size_t)(b0 + pr[i]) * DIM + pc[i]);

    for (int s = 0; s < NSTG; ++s) {
        float* buf = xs[s & 1];
        #pragma unroll
        for (int i = 0; i < 3; ++i)
            *reinterpret_cast<float4*>(&buf[(i * 256 + t) * 4]) = pf[i];
        __syncthreads();   // writers of buf done; stage s+1 writes the OTHER buffer

        if (s + 1 < NSTG) {                 // prefetch next stage; consumer is
            int rb = b0 + (s + 1) * RSTG;   // a ds_write past this stage's compute
            #pragma unroll
            for (int i = 0; i < 3; ++i)
                pf[i] = *reinterpret_cast<const float4*>(
                    xh + (size_t)(rb + pr[i]) * DIM + pc[i]);
        }

        // ---- phase A: 8 winner computations -> kg8[] ----
        int kg8[RSTG];
        #pragma unroll
        for (int r = 0; r < RSTG; ++r) {
            const float* xr = &buf[r * HALFF + mloc * D_SUB];  // quad-broadcast
            float2 x01 = *reinterpret_cast<const float2*>(xr);
            float2 x23 = *reinterpret_cast<const float2*>(xr + 2);
            float2 x45 = *reinterpret_cast<const float2*>(xr + 4);
            float xv[6] = {x01.x, x01.y, x23.x, x23.y, x45.x, x45.y};
            v2f xxe[6];
            #pragma unroll
            for (int e = 0; e < 6; ++e) xxe[e] = (v2f){xv[e], xv[e]};

            float best1 = -FLT_MAX, best2 = -FLT_MAX;
            int   kg    = kq * 8;
            #pragma unroll
            for (int p = 0; p < 4; ++p) {
                v2f acc = cpk[p][0] * xxe[0];
                #pragma unroll
                for (int e = 1; e < 6; ++e)
                    acc = __builtin_elementwise_fma(cpk[p][e], xxe[e], acc);
                #pragma unroll
                for (int h = 0; h < 2; ++h) {         // j = 2p+h, ascending
                    float d  = h ? acc.y : acc.x;
                    bool  gt = d > best1;             // strict > => first wins
                    best2 = gt ? best1 : fmaxf(best2, d);
                    kg    = gt ? (kq * 8 + 2*p + h) : kg;
                    best1 = gt ? d : best1;
                }
            }

            // Quad butterfly via DPP (pure VALU).
            {
                float o1 = dppf<DPP_XOR1>(best1);
                float o2 = dppf<DPP_XOR1>(best2);
                int   ok = dppi<DPP_XOR1>(kg);
                bool take = (o1 > best1) || (o1 == best1 && ok < kg);
                best2 = fmaxf(fminf(best1, o1), fmaxf(best2, o2));
                kg    = take ? ok : kg;
                best1 = fmaxf(best1, o1);
            }
            {
                float o1 = dppf<DPP_XOR2>(best1);
                float o2 = dppf<DPP_XOR2>(best2);
                int   ok = dppi<DPP_XOR2>(kg);
                bool take = (o1 > best1) || (o1 == best1 && ok < kg);
                best2 = fmaxf(fminf(best1, o1), fmaxf(best2, o2));
                kg    = take ? ok : kg;
                best1 = fmaxf(best1, o1);
            }

            // Near-tie (quad-uniform, ~0.1%): exact fp64 argmax over 32 codes.
            if (best1 - best2 < 1e-5f) {
                const float* crow = cb + (size_t)m * K_CB * D_SUB;
                double db = -1e300; int dkg = 0;
                for (int k2 = 0; k2 < K_CB; ++k2) {
                    double sa = 0.0;
                    for (int e = 0; e < 6; ++e)
                        sa = fma((double)crow[k2*6+e], (double)xv[e], sa);
                    if (sa > db) { db = sa; dkg = k2; }
                }
                kg = dkg;
            }
            kg8[r] = kg;
        }

        // ---- phase B: 8 independent winner gathers (cb is L1/L2-hot) ----
        const bool act = (kq < 3);
        float2 gv[RSTG];
        if (act) {
            #pragma unroll
            for (int r = 0; r < RSTG; ++r)
                gv[r] = *(reinterpret_cast<const float2*>(
                    cb + ((size_t)m * K_CB + (size_t)kg8[r]) * D_SUB) + kq);
        }

        __builtin_amdgcn_sched_barrier(0);  // keep all gathers above all stores

        // ---- phase C: 8 coalesced float2 stores (48/64 lanes -> full lines) ----
        if (act) {
            #pragma unroll
            for (int r = 0; r < RSTG; ++r) {
                float* dst = oh + (size_t)(b0 + s * RSTG + r) * DIM + mloc * D_SUB;
                *(reinterpret_cast<float2*>(dst) + kq) = gv[r];
            }
        }
    }
}

extern "C" void kernel_launch(void* const* d_in, const int* in_sizes, int n_in,
                              void* d_out, int out_size, void* d_ws, size_t ws_size,
                              hipStream_t stream) {
    const float* x  = (const float*)d_in[0];   // (32768, 768) fp32
    const float* cb = (const float*)d_in[1];   // (128, 32, 6) fp32
    float* out = (float*)d_out;                // (32768, 768) fp32

    dim3 grid(BATCH / BROWS, 2);   // 2048 x 2 = 4096 blocks
    dim3 block(256);               // 64 m x 4 k-quarters
    hipLaunchKernelGGL(pq_head_kernel, grid, block, 0, stream, x, cb, out);
}